// Round 4
// baseline (927.169 us; speedup 1.0000x reference)
//
#include <hip/hip_runtime.h>
#include <hip/hip_bf16.h>

// Joiner: out[m, v] = tanh(enc[b_m, t_m, :] + dec[b_m, u_m, :]) @ W[v, :]^T + bias[v]
// M ~ 295k, K = 512, V = 500 (padded 512).
// Persistent-chunk blocks (512 thr, 8 waves), 64-row tiles, single-buffer A in LDS,
// register-staged gather pipelined under GEMM, depth-3 B register prefetch,
// coalesced epilogue via 32 KB Obuf.

typedef __attribute__((ext_vector_type(8))) short short8;       // 8 bf16
typedef __attribute__((ext_vector_type(4))) float f32x4;        // MFMA acc
typedef __attribute__((ext_vector_type(4))) unsigned int u32x4; // 16B LDS write

__device__ __forceinline__ unsigned short f2bf(float v) {
    unsigned int u = __float_as_uint(v);
    u += 0x7fffu + ((u >> 16) & 1u);
    return (unsigned short)(u >> 16);
}

__device__ __forceinline__ float tanh_fast(float x) {
    // tanh(x) = sign(x) * (1 - 2^(-2*log2(e)*|x|)) / (1 + same)
    float e = __builtin_amdgcn_exp2f(fabsf(x) * -2.8853900817779268f);
    float r = (1.0f - e) * __builtin_amdgcn_rcpf(1.0f + e);
    return copysignf(r, x);
}

// W (500x512 f32) -> 512x512 bf16 (rows 500..511 zero) in workspace.
__global__ void prep_w_kernel(const float* __restrict__ W, unsigned short* __restrict__ Wbf) {
    const int i = blockIdx.x * blockDim.x + threadIdx.x;
    const int base = i << 2;
    const int n = base >> 9;
    const int k = base & 511;
    float4 v = make_float4(0.f, 0.f, 0.f, 0.f);
    if (n < 500) v = *reinterpret_cast<const float4*>(W + ((size_t)n << 9) + k);
    uint2 p;
    p.x = (unsigned int)f2bf(v.x) | ((unsigned int)f2bf(v.y) << 16);
    p.y = (unsigned int)f2bf(v.z) | ((unsigned int)f2bf(v.w) << 16);
    *reinterpret_cast<uint2*>(Wbf + base) = p;
}

template<bool USE_WS>
__global__ __launch_bounds__(512, 2)
void joiner_kernel(const float* __restrict__ enc, const float* __restrict__ dec,
                   const float* __restrict__ W, const float* __restrict__ bias,
                   const int* __restrict__ b_idx, const int* __restrict__ t_idx,
                   const int* __restrict__ u_idx, const unsigned short* __restrict__ Wbf,
                   float* __restrict__ out, int M, int nt, int chunk)
{
    __shared__ unsigned short Abuf[64 * 512];   // 64 KB bf16, XOR-swizzled
    __shared__ float Obuf[16 * 512];            // 32 KB epilogue staging

    const int tid  = threadIdx.x;
    const int wv   = tid >> 6;       // wave 0..7 -> cols wv*64..+64
    const int lane = tid & 63;
    const int l15  = lane & 15;
    const int lk   = lane >> 4;

    int bid = blockIdx.x;
    bid = (bid & 7) * 64 + (bid >> 3);          // XCD-contiguous tile ranges
    const int t0 = bid * chunk;
    const int t1 = min(t0 + chunk, nt);
    if (t0 >= t1) return;

    // ---- gather mapping: thread -> (row 0..63, 64-col segment 0..7) ----
    const int grow = tid >> 3;
    const int gseg = tid & 7;
    const int gsw  = ((grow ^ gseg) & 7) << 4;  // LDS chunk swizzle

    // ---- per-wave bias ----
    float bvals[4];
    #pragma unroll
    for (int nf = 0; nf < 4; ++nf) {
        const int c = wv * 64 + nf * 16 + l15;
        bvals[nf] = (c < 500) ? bias[c] : 0.0f;
    }

    // ---- B pointers ----
    const unsigned short* wb = Wbf + ((size_t)(wv * 64 + l15)) * 512 + lk * 8;
    const float* wbf32 = W + ((size_t)(wv * 64 + l15)) * 512 + lk * 8;

    auto loadB = [&](int ks, int nf) -> short8 {
        if constexpr (USE_WS) {
            return *reinterpret_cast<const short8*>(wb + (size_t)nf * 8192 + ks * 32);
        } else {
            short8 b;
            float4 w0 = make_float4(0,0,0,0), w1 = make_float4(0,0,0,0);
            if (wv * 64 + nf * 16 + l15 < 500) {
                const float4* q = reinterpret_cast<const float4*>(wbf32 + (size_t)nf * 8192 + ks * 32);
                w0 = q[0]; w1 = q[1];
            }
            b[0] = (short)f2bf(w0.x); b[1] = (short)f2bf(w0.y);
            b[2] = (short)f2bf(w0.z); b[3] = (short)f2bf(w0.w);
            b[4] = (short)f2bf(w1.x); b[5] = (short)f2bf(w1.y);
            b[6] = (short)f2bf(w1.z); b[7] = (short)f2bf(w1.w);
            return b;
        }
    };

    // ---- producer state ----
    int ib = 0, it = 0, iu = 0;                 // idx regs for next tile to produce
    const float *ep = enc, *dp = dec;           // row base ptrs for the tile in flight
    float4 geA[4], gdA[4], geB[4], gdB[4];      // ping-pong gather quarters

    auto load_idx = [&](int t) {
        const int row = min(t * 64 + grow, M - 1);
        ib = b_idx[row]; it = t_idx[row]; iu = u_idx[row];
    };
    auto set_base = [&]() {
        ep = enc + (((size_t)ib * 512 + it) << 9) + gseg * 64;
        dp = dec + (((size_t)ib * 64  + iu) << 9) + gseg * 64;
    };
    auto issueA = [&](int q) {
        const float4* e4 = reinterpret_cast<const float4*>(ep + q * 16);
        const float4* d4 = reinterpret_cast<const float4*>(dp + q * 16);
        #pragma unroll
        for (int i = 0; i < 4; ++i) { geA[i] = e4[i]; gdA[i] = d4[i]; }
    };
    auto issueB = [&](int q) {
        const float4* e4 = reinterpret_cast<const float4*>(ep + q * 16);
        const float4* d4 = reinterpret_cast<const float4*>(dp + q * 16);
        #pragma unroll
        for (int i = 0; i < 4; ++i) { geB[i] = e4[i]; gdB[i] = d4[i]; }
    };
    auto consume = [&](const float4* e4, const float4* d4, int q) {
        float v[16];
        #pragma unroll
        for (int i = 0; i < 4; ++i) {
            v[i*4+0] = tanh_fast(e4[i].x + d4[i].x);
            v[i*4+1] = tanh_fast(e4[i].y + d4[i].y);
            v[i*4+2] = tanh_fast(e4[i].z + d4[i].z);
            v[i*4+3] = tanh_fast(e4[i].w + d4[i].w);
        }
        unsigned pw[8];
        #pragma unroll
        for (int i = 0; i < 8; ++i)
            pw[i] = (unsigned)f2bf(v[2*i]) | ((unsigned)f2bf(v[2*i+1]) << 16);
        const int base = grow * 1024 + gseg * 128 + q * 32;
        u32x4 c0 = {pw[0], pw[1], pw[2], pw[3]};
        u32x4 c1 = {pw[4], pw[5], pw[6], pw[7]};
        *reinterpret_cast<u32x4*>(reinterpret_cast<char*>(Abuf) + ((base     ) ^ gsw)) = c0;
        *reinterpret_cast<u32x4*>(reinterpret_cast<char*>(Abuf) + ((base + 16) ^ gsw)) = c1;
    };
    auto produce = [&]() {       // quarter 0 already in flight in set A
        issueB(1); consume(geA, gdA, 0);
        issueA(2); consume(geB, gdB, 1);
        issueB(3); consume(geA, gdA, 2);
        consume(geB, gdB, 3);
    };

    // ---- chunk prologue: produce A(t0) ----
    load_idx(t0); set_base(); issueA(0);
    produce();
    if (t0 + 1 < t1) load_idx(t0 + 1);
    __syncthreads();

    short8 Bf[4][4];

    for (int t = t0; t < t1; ++t) {
        const bool hasNext = (t + 1 < t1);
        if (hasNext) { set_base(); issueA(0); }   // gather q0(t+1) rides under GEMM(t)

        // ---- GEMM(t): 16 K-steps, depth-3 B register pipeline ----
        f32x4 acc[4][4];
        #pragma unroll
        for (int mf = 0; mf < 4; ++mf)
            #pragma unroll
            for (int nf = 0; nf < 4; ++nf)
                acc[mf][nf] = (f32x4)(0.0f);

        #pragma unroll
        for (int ks = 0; ks < 4; ++ks)
            #pragma unroll
            for (int nf = 0; nf < 4; ++nf)
                Bf[ks][nf] = loadB(ks, nf);

        #pragma unroll
        for (int ks = 0; ks < 16; ++ks) {
            short8 a[4];
            #pragma unroll
            for (int mf = 0; mf < 4; ++mf) {
                int byte = (mf * 16 + l15) * 1024 + ks * 64 + lk * 16;
                byte ^= ((l15 ^ (ks >> 1)) & 7) << 4;
                a[mf] = *reinterpret_cast<const short8*>(reinterpret_cast<const char*>(Abuf) + byte);
            }
            __builtin_amdgcn_s_setprio(1);
            #pragma unroll
            for (int mf = 0; mf < 4; ++mf)
                #pragma unroll
                for (int nf = 0; nf < 4; ++nf)
                    acc[mf][nf] = __builtin_amdgcn_mfma_f32_16x16x32_bf16(a[mf], Bf[ks & 3][nf], acc[mf][nf], 0, 0, 0);
            __builtin_amdgcn_s_setprio(0);
            if (ks < 12)
                #pragma unroll
                for (int nf = 0; nf < 4; ++nf)
                    Bf[ks & 3][nf] = loadB(ks + 4, nf);
        }

        if (t + 2 < t1) load_idx(t + 2);   // idx latency hides under epilogue

        // ---- epilogue(t): 4 passes of 16 rows through Obuf ----
        const int rowbase = t * 64;
        #pragma unroll
        for (int p = 0; p < 4; ++p) {
            #pragma unroll
            for (int nf = 0; nf < 4; ++nf)
                #pragma unroll
                for (int j = 0; j < 4; ++j) {
                    const int r16 = lk * 4 + j;
                    const int idx = (r16 * 512 + wv * 64 + nf * 16 + l15) ^ (j << 4);
                    Obuf[idx] = acc[p][nf][j] + bvals[nf];
                }
            __syncthreads();
            {
                const int r16 = tid >> 5;
                const int gcol = (tid & 31) * 4;
                const int row = rowbase + p * 16 + r16;
                #pragma unroll
                for (int i = 0; i < 4; ++i) {
                    const int col = gcol + i * 128;
                    const int idx = (r16 * 512 + col) ^ ((r16 & 3) << 4);
                    if (row < M && col < 500) {
                        const float4 v = *reinterpret_cast<const float4*>(&Obuf[idx]);
                        *reinterpret_cast<float4*>(&out[(size_t)row * 500 + col]) = v;
                    }
                }
            }
            __syncthreads();
        }

        // ---- produce A(t+1): q0 in flight since before GEMM ----
        if (hasNext) produce();
        __syncthreads();
    }
}

extern "C" void kernel_launch(void* const* d_in, const int* in_sizes, int n_in,
                              void* d_out, int out_size, void* d_ws, size_t ws_size,
                              hipStream_t stream) {
    const float* enc  = (const float*)d_in[0];
    const float* dec  = (const float*)d_in[1];
    const float* W    = (const float*)d_in[2];
    const float* bias = (const float*)d_in[3];
    const int* bi = (const int*)d_in[4];
    const int* ti = (const int*)d_in[5];
    const int* ui = (const int*)d_in[6];
    float* out = (float*)d_out;

    const int M = in_sizes[4];
    const int nt = (M + 63) / 64;
    const int grid = 512;
    const int chunk = (nt + grid - 1) / grid;

    if (ws_size >= (size_t)(512 * 512 * 2)) {
        prep_w_kernel<<<256, 256, 0, stream>>>(W, (unsigned short*)d_ws);
        joiner_kernel<true><<<grid, 512, 0, stream>>>(
            enc, dec, W, bias, bi, ti, ui, (const unsigned short*)d_ws, out, M, nt, chunk);
    } else {
        joiner_kernel<false><<<grid, 512, 0, stream>>>(
            enc, dec, W, bias, bi, ti, ui, nullptr, out, M, nt, chunk);
    }
}

// Round 5
// 460.208 us; speedup vs baseline: 2.0147x; 2.0147x over previous
//
#include <hip/hip_runtime.h>
#include <hip/hip_bf16.h>

// Joiner: out[m, v] = tanh(enc[b_m, t_m, :] + dec[b_m, u_m, :]) @ W[v, :]^T + bias[v]
// M ~ 295k rows, K = 512, V = 500 (padded to 512).
// r3 data flow (proven): coalesced full-row gather, XOR-swizzled A in LDS,
// global->reg B with depth-1 prefetch, union-Obuf coalesced epilogue.
// r5 change: 8 waves x (64x64) wave tiles, VGPR<=128 -> 4 waves/SIMD (2x r3).

typedef __attribute__((ext_vector_type(8))) short short8;   // 8 bf16
typedef __attribute__((ext_vector_type(4))) float f32x4;    // MFMA acc

__device__ __forceinline__ unsigned short f2bf(float v) {
    unsigned int u = __float_as_uint(v);
    u += 0x7fffu + ((u >> 16) & 1u);
    return (unsigned short)(u >> 16);
}

__device__ __forceinline__ float tanh_fast(float x) {
    float e = __builtin_amdgcn_exp2f(fabsf(x) * -2.8853900817779268f);
    float r = (1.0f - e) * __builtin_amdgcn_rcpf(1.0f + e);
    return copysignf(r, x);
}

// W (500x512 f32) -> 512x512 bf16 (rows 500..511 zero) in workspace.
__global__ void prep_w_kernel(const float* __restrict__ W, unsigned short* __restrict__ Wbf) {
    const int i = blockIdx.x * blockDim.x + threadIdx.x;
    const int base = i << 2;
    const int n = base >> 9;
    const int k = base & 511;
    float4 v = make_float4(0.f, 0.f, 0.f, 0.f);
    if (n < 500) v = *reinterpret_cast<const float4*>(W + ((size_t)n << 9) + k);
    uint2 p;
    p.x = (unsigned int)f2bf(v.x) | ((unsigned int)f2bf(v.y) << 16);
    p.y = (unsigned int)f2bf(v.z) | ((unsigned int)f2bf(v.w) << 16);
    *reinterpret_cast<uint2*>(Wbf + base) = p;
}

// Block: 64 rows x 512 cols. 512 threads = 8 waves, wave tile 64x64.
template<bool USE_WS>
__global__ __launch_bounds__(512, 4)
void joiner_gemm_kernel(const float* __restrict__ enc, const float* __restrict__ dec,
                        const float* __restrict__ W, const float* __restrict__ bias,
                        const int* __restrict__ b_idx, const int* __restrict__ t_idx,
                        const int* __restrict__ u_idx,
                        const unsigned short* __restrict__ Wbf,
                        float* __restrict__ out, int M)
{
    // Union: phase1/2 = [64][512] bf16 (64KB, XOR-swizzled); epilogue = [64][257] f32.
    __shared__ unsigned char Abuf[65792];
    __shared__ unsigned int eoffs[64];
    __shared__ unsigned int doffs[64];

    const int tid = threadIdx.x;

    // Bijective XCD-contiguous block swizzle (consecutive tiles -> same XCD L2).
    int bid = blockIdx.x;
    {
        const int nwg = gridDim.x;
        const int q = nwg >> 3, r = nwg & 7;
        const int x = bid & 7, j = bid >> 3;
        bid = (x < r ? x * (q + 1) : r * (q + 1) + (x - r) * q) + j;
    }
    const int m0 = bid * 64;

    // ------- Phase 0: gather offsets -------
    if (tid < 64) {
        const int rc = min(m0 + tid, M - 1);
        const unsigned bi = (unsigned)b_idx[rc];
        eoffs[tid] = ((bi << 9) + (unsigned)t_idx[rc]) << 9;   // (bi*512+ti)*512
        doffs[tid] = ((bi << 6) + (unsigned)u_idx[rc]) << 9;   // (bi*64 +ui)*512
    }
    __syncthreads();

    // ------- Phase 1: activations -> LDS (bf16), 4 rows/pass, depth-3 pipeline -------
    {
        const int rr = tid >> 7;          // 0..3 : row within quad
        const int kq = tid & 127;         // float4 chunk in 512-wide row
        const int kq4 = kq << 2;

        float4 es[3], dsv[3];
        #pragma unroll
        for (int i = 0; i < 3; ++i) {
            es[i]  = *reinterpret_cast<const float4*>(enc + eoffs[i * 4 + rr] + kq4);
            dsv[i] = *reinterpret_cast<const float4*>(dec + doffs[i * 4 + rr] + kq4);
        }
        #pragma unroll
        for (int p = 0; p < 16; ++p) {
            const int s = p % 3;
            const float4 e = es[s];
            const float4 d = dsv[s];
            if (p + 3 < 16) {
                es[s]  = *reinterpret_cast<const float4*>(enc + eoffs[(p + 3) * 4 + rr] + kq4);
                dsv[s] = *reinterpret_cast<const float4*>(dec + doffs[(p + 3) * 4 + rr] + kq4);
            }
            uint2 packed;
            packed.x = (unsigned int)f2bf(tanh_fast(e.x + d.x)) |
                       ((unsigned int)f2bf(tanh_fast(e.y + d.y)) << 16);
            packed.y = (unsigned int)f2bf(tanh_fast(e.z + d.z)) |
                       ((unsigned int)f2bf(tanh_fast(e.w + d.w)) << 16);
            const int r = p * 4 + rr;
            const int byteoff = (r * 1024 + kq * 8) ^ ((r & 7) << 4);
            *reinterpret_cast<uint2*>(&Abuf[byteoff]) = packed;
        }
    }

    // ------- Phase 2: MFMA GEMM, wave tile 64x64, depth-1 B prefetch -------
    const int lane = tid & 63;
    const int wv   = tid >> 6;          // wave 0..7 -> cols [wv*64, wv*64+64)
    const int l15  = lane & 15;
    const int lk   = lane >> 4;
    const int n_wave = wv << 6;
    const int a_swz  = (l15 & 7) << 4;

    f32x4 acc[4][4];
    #pragma unroll
    for (int mf = 0; mf < 4; ++mf)
        #pragma unroll
        for (int nf = 0; nf < 4; ++nf)
            acc[mf][nf] = (f32x4)(0.0f);

    const unsigned short* wp = USE_WS ? (Wbf + (((size_t)(n_wave + l15)) << 9) + (lk << 3)) : nullptr;
    const float* wpf = USE_WS ? nullptr : (W + (((size_t)(n_wave + l15)) << 9) + (lk << 3));
    const int colbase = n_wave + l15;

    auto loadB = [&](int ks, int nf) -> short8 {
        if constexpr (USE_WS) {
            return *reinterpret_cast<const short8*>(wp + nf * 8192 + ks * 32);
        } else {
            short8 b;
            float4 w0 = make_float4(0,0,0,0), w1 = make_float4(0,0,0,0);
            if (colbase + nf * 16 < 500) {
                const float4* q = reinterpret_cast<const float4*>(wpf + nf * 8192 + ks * 32);
                w0 = q[0]; w1 = q[1];
            }
            b[0] = (short)f2bf(w0.x); b[1] = (short)f2bf(w0.y);
            b[2] = (short)f2bf(w0.z); b[3] = (short)f2bf(w0.w);
            b[4] = (short)f2bf(w1.x); b[5] = (short)f2bf(w1.y);
            b[6] = (short)f2bf(w1.z); b[7] = (short)f2bf(w1.w);
            return b;
        }
    };

    short8 Bc[4], Bn[4];
    #pragma unroll
    for (int nf = 0; nf < 4; ++nf) Bc[nf] = loadB(0, nf);

    __syncthreads();

    #pragma unroll 4
    for (int ks = 0; ks < 16; ++ks) {
        if (ks < 15) {
            #pragma unroll
            for (int nf = 0; nf < 4; ++nf) Bn[nf] = loadB(ks + 1, nf);
        }
        short8 a[4];
        #pragma unroll
        for (int mf = 0; mf < 4; ++mf) {
            const int addr = (((mf * 16 + l15) << 10) + ks * 64 + lk * 16) ^ a_swz;
            a[mf] = *reinterpret_cast<const short8*>(&Abuf[addr]);
        }
        __builtin_amdgcn_s_setprio(1);
        #pragma unroll
        for (int mf = 0; mf < 4; ++mf)
            #pragma unroll
            for (int nf = 0; nf < 4; ++nf)
                acc[mf][nf] = __builtin_amdgcn_mfma_f32_16x16x32_bf16(a[mf], Bc[nf], acc[mf][nf], 0, 0, 0);
        __builtin_amdgcn_s_setprio(0);
        #pragma unroll
        for (int nf = 0; nf < 4; ++nf) Bc[nf] = Bn[nf];
    }

    // ------- Epilogue: bias (loaded here to cut GEMM liveness) + coalesced stores -------
    #pragma unroll
    for (int nf = 0; nf < 4; ++nf) {
        const int col = n_wave + nf * 16 + l15;
        const float bv = (col < 500) ? bias[col] : 0.0f;
        #pragma unroll
        for (int mf = 0; mf < 4; ++mf)
            #pragma unroll
            for (int j = 0; j < 4; ++j)
                acc[mf][nf][j] += bv;
    }

    float* Obuf = reinterpret_cast<float*>(Abuf);   // [64][257] f32
    #pragma unroll
    for (int h = 0; h < 2; ++h) {
        __syncthreads();                  // protects Abuf/Obuf reuse
        if ((wv >> 2) == h) {
            const int lcol = (wv & 3) << 6;
            #pragma unroll
            for (int mf = 0; mf < 4; ++mf)
                #pragma unroll
                for (int nf = 0; nf < 4; ++nf)
                    #pragma unroll
                    for (int j = 0; j < 4; ++j) {
                        const int r = mf * 16 + lk * 4 + j;
                        Obuf[r * 257 + lcol + nf * 16 + l15] = acc[mf][nf][j];
                    }
        }
        __syncthreads();
        // 64 rows x 64 float4-chunks per half; each wave stores 1KB contiguous per iter
        #pragma unroll
        for (int i = 0; i < 8; ++i) {
            const int linear = i * 512 + tid;
            const int r  = linear >> 6;
            const int c4 = linear & 63;
            const int row = m0 + r;
            const int col = (h << 8) + (c4 << 2);
            if (row < M && col < 500) {
                const float4 v = *reinterpret_cast<const float4*>(&Obuf[r * 257 + (c4 << 2)]);
                *reinterpret_cast<float4*>(&out[(size_t)row * 500 + col]) = v;
            }
        }
    }
}

extern "C" void kernel_launch(void* const* d_in, const int* in_sizes, int n_in,
                              void* d_out, int out_size, void* d_ws, size_t ws_size,
                              hipStream_t stream) {
    const float* enc  = (const float*)d_in[0];
    const float* dec  = (const float*)d_in[1];
    const float* W    = (const float*)d_in[2];
    const float* bias = (const float*)d_in[3];
    const int* bi = (const int*)d_in[4];
    const int* ti = (const int*)d_in[5];
    const int* ui = (const int*)d_in[6];
    float* out = (float*)d_out;

    const int M = in_sizes[4];
    const int grid = (M + 63) / 64;

    if (ws_size >= (size_t)(512 * 512 * 2)) {
        prep_w_kernel<<<256, 256, 0, stream>>>(W, (unsigned short*)d_ws);
        joiner_gemm_kernel<true><<<grid, 512, 0, stream>>>(
            enc, dec, W, bias, bi, ti, ui, (const unsigned short*)d_ws, out, M);
    } else {
        joiner_gemm_kernel<false><<<grid, 512, 0, stream>>>(
            enc, dec, W, bias, bi, ti, ui, nullptr, out, M);
    }
}